// Round 11
// baseline (127.800 us; speedup 1.0000x reference)
//
#include <hip/hip_runtime.h>
#include <math.h>

// ---- problem constants ----
constexpr int cB   = 64;
constexpr int cC   = 20;
constexpr int cNA  = 5;
constexpr int cH   = 19;
constexpr int cW   = 19;
constexpr int cT   = 50;
constexpr int cNB  = cB * cC;          // 1280
constexpr int cHW  = cH * cW;          // 361
constexpr int cA4  = cNA * cHW;        // 1805
constexpr int cCH  = cNA * 6;          // 30 channels
constexpr long cNTOT = (long)cNB * cA4; // 2,310,400
constexpr int cCLS_BLOCKS = cB * cNA;  // 320

// ---- anchors: compile-time (match setup_inputs exactly) ----
__device__ __constant__ float cAW[cNA]   = {1.3221f, 3.19275f, 5.05587f, 9.47112f, 11.2364f};
__device__ __constant__ float cAH[cNA]   = {1.73145f, 4.00944f, 8.09892f, 4.84053f, 10.0071f};
__device__ __constant__ float cAREA[cNA] = {2.28930345f, 12.80114796f, 40.94706183f, 45.84455262f, 112.44377644f};
__device__ __constant__ float cLNAW[cNA] = {0.27920469f, 1.16088088f, 1.62060702f, 2.24822684f, 2.41915174f};
__device__ __constant__ float cLNAH[cNA] = {0.54896100f, 1.38865236f, 2.09173157f, 1.57701337f, 2.30329495f};

// ---- workspace layout (bytes) ----
constexpr int ACC_BANKS = 64;
constexpr size_t OFF_CNT = 2560;                // after 5*64 doubles
constexpr size_t OFF_ROW = 4096;                // rowenc: cB*cA4 ints = 462080 B
constexpr size_t ZERO_BYTES = OFF_ROW + (size_t)cB * cA4 * 4;   // 466176 (16-divisible)
constexpr int    ZERO_INT4  = (int)(ZERO_BYTES / 16);           // 29136
// box tables (fully overwritten by k_init; NOT zeroed)
constexpr size_t OFF_GB4 = 466432;                               // uint4 [cNB*cT] splat2 l,r,t,b
constexpr size_t OFF_GB1 = OFF_GB4 + (size_t)cNB * cT * 16;      // u32   [cNB*cT] splat2 -0.6*ga
constexpr size_t WS_NEEDED = OFF_GB1 + (size_t)cNB * cT * 4;     // 1,746,432

// ---- fast transcendentals (raw HW ops) ----
__device__ __forceinline__ float fexp(float x) {
    return __builtin_amdgcn_exp2f(x * 1.4426950408889634f);
}
__device__ __forceinline__ float flog(float x) {
    return __builtin_amdgcn_logf(x) * 0.6931471805599453f;
}
__device__ __forceinline__ float frcp(float x) { return __builtin_amdgcn_rcpf(x); }

// ---- packed f16 helpers ----
typedef _Float16 h2 __attribute__((ext_vector_type(2)));
union HU { unsigned u; h2 h; };
__device__ __forceinline__ unsigned splat2(float v) {
    HU x; _Float16 f = (_Float16)v; x.h[0] = f; x.h[1] = f; return x.u;
}
// boxes pre-scaled by sqrt(1.6): inner test is pk_fma(iw,ih,-0.6ga) > 0.6pa
constexpr float cS = 1.2649110640673518f;   // sqrt(1.6)

// =====================================================================
// K0 (init): replaces BOTH the memset node and k_prep.  (R8 verbatim)
// =====================================================================
__launch_bounds__(256)
__global__ void k_init(const float* __restrict__ target, int4* __restrict__ wsz,
                       uint4* __restrict__ gb4, unsigned* __restrict__ gb1) {
    const int gtid = blockIdx.x * 256 + threadIdx.x;
    int4 z4; z4.x = z4.y = z4.z = z4.w = 0;
    for (int k = gtid; k < ZERO_INT4; k += cCLS_BLOCKS * 256) wsz[k] = z4;

    const int nb = blockIdx.x * 4 + (threadIdx.x >> 6);
    const int t  = threadIdx.x & 63;
    float xr = 1.f, yr = 0.f, wr = 0.f, hr = 0.f;
    const bool isT = (t < cT);
    if (isT) {
        const float* tg = target + (size_t)nb * (cT * 5) + t * 5;
        xr = tg[1]; yr = tg[2]; wr = tg[3]; hr = tg[4];
    }
    unsigned long long nz = __ballot(xr != 0.0f);
    if (isT) {
        unsigned long long below = (2ull << t) - 1ull;
        bool valid = ((~nz) & below) == 0ull;
        const int idx = nb * cT + t;
        float gx = xr * (float)cW, gy = yr * (float)cH;
        float gw = wr * (float)cW, gh = hr * (float)cH;
        uint4 bx;
        if (valid) {
            bx.x = splat2(cS * (gx - 0.5f * gw));
            bx.y = splat2(cS * (gx + 0.5f * gw));
            bx.z = splat2(cS * (gy - 0.5f * gh));
            bx.w = splat2(cS * (gy + 0.5f * gh));
            gb1[idx] = splat2(-0.6f * (gw * gh));
        } else {                              // degenerate: inter == 0
            bx.x = splat2(1e4f);  bx.y = splat2(-1e4f);
            bx.z = splat2(1e4f);  bx.w = splat2(-1e4f);
            gb1[idx] = splat2(0.0f);
        }
        gb4[idx] = bx;
    }
}

// =====================================================================
// K1: per-cell losses. (R10 structure; Phase A split into LOAD pass +
// COMPUTE pass with named register arrays — forces the compiler to
// batch all 20 global loads + 4 LDS reads, one latency wait not four)
// =====================================================================
template<bool GB>
__launch_bounds__(256, 4)
__global__ void k_main(const float* __restrict__ outp, const float* __restrict__ target,
                       const uint4* __restrict__ gb4, const unsigned* __restrict__ gb1,
                       int* __restrict__ rowenc, double* __restrict__ acc) {
    __shared__ int s_win[1024];                      // windowed winner table
    __shared__ float4 s_gt[cT];                      // gx,gy,gw,gh
    __shared__ __align__(16) unsigned s_box[GB ? 1 : cT][8];  // fallback only
    __shared__ double s_red[3][4];
    const int tid  = threadIdx.x;
    // 2560 = 8 XCD-chunks of 320; halves of an nb stay on one XCD
    const int swz  = ((int)(blockIdx.x & 7)) * 320 + ((int)blockIdx.x >> 3);
    const int nb   = swz >> 1;
    const int half = swz & 1;
    const int winoff = half << 10;
    const int base = winoff + tid;                   // 0..1023 / 1024..2047
    const int b_   = nb / cC;
    const int c_   = nb - b_ * cC;
    const float* obase = outp + (size_t)nb * (cCH * cHW);
    const int nbT = nb * cT;

    s_win[tid] = -1; s_win[tid + 256] = -1;
    s_win[tid + 512] = -1; s_win[tid + 768] = -1;
    __syncthreads();

    // ---- light prep (wave 0; both halves duplicate) ----
    int myCell = -1;                                 // register-carried winner cell
    if (tid < 64) {
        const int t = tid;
        float xr = 1.f, yr = 0.f, wr = 0.f, hr = 0.f;
        if (t < cT) {
            const float* tg = target + (size_t)nb * (cT * 5) + t * 5;
            xr = tg[1]; yr = tg[2]; wr = tg[3]; hr = tg[4];
        }
        unsigned long long nz = __ballot(xr != 0.0f);
        if (t < cT) {
            unsigned long long below = (2ull << t) - 1ull;
            bool valid = ((~nz) & below) == 0ull;
            float gx = xr * (float)cW, gy = yr * (float)cH;
            float gw = wr * (float)cW, gh = hr * (float)cH;
            s_gt[t] = make_float4(gx, gy, gw, gh);
            if (valid) {
                float garea = gw * gh;
                float best = -1.0f; int bn = 0;
                for (int n = 0; n < cNA; ++n) {
                    float inter = fminf(gw, cAW[n]) * fminf(gh, cAH[n]);
                    float uni   = garea + cAREA[n] - inter;
                    float r = inter / fmaxf(uni, 1e-12f);
                    if (r > best) { best = r; bn = n; }
                }
                int cell = bn * cHW + (int)gy * cW + (int)gx;
                myCell = cell;
                if constexpr (!GB) {
                    s_box[t][0] = splat2(cS * (gx - 0.5f * gw));
                    s_box[t][1] = splat2(cS * (gx + 0.5f * gw));
                    s_box[t][2] = splat2(cS * (gy - 0.5f * gh));
                    s_box[t][3] = splat2(cS * (gy + 0.5f * gh));
                    s_box[t][4] = splat2(-0.6f * garea);
                }
                if (cell >= winoff && cell < winoff + 1024)
                    atomicMax(&s_win[cell - winoff], t);
            } else if constexpr (!GB) {
                s_box[t][0] = splat2(1e4f);  s_box[t][1] = splat2(-1e4f);
                s_box[t][2] = splat2(1e4f);  s_box[t][3] = splat2(-1e4f);
                s_box[t][4] = splat2(0.0f);
            }
        }
    }
    __syncthreads();
    // rowenc emission: winner of each in-window cell emits (exactly-once)
    if (tid < cT && myCell >= winoff && myCell < winoff + 1024 &&
        s_win[myCell - winoff] == tid)
        atomicAdd(&rowenc[b_ * cA4 + myCell], (1 << 10) | (c_ * cT + tid));

    // ---- Phase A pass 1: batched LOADS into named register arrays ----
    float xl4[4], yl4[4], wl4[4], hl4[4], cl4[4];
    int   na4[4], i4[4], j4[4], wt4[4];
    #pragma unroll
    for (int u = 0; u < 4; ++u) {
        int cell = base + (u << 8);
        int cc   = (cell < cA4) ? cell : (cA4 - 1);
        int na   = cc / cHW;
        int rem  = cc - na * cHW;
        int j    = rem / cW;
        na4[u] = na; j4[u] = j; i4[u] = rem - j * cW;
        const float* ob = obase + (size_t)(na * 6) * cHW + rem;
        xl4[u] = ob[0];
        yl4[u] = ob[cHW];
        wl4[u] = ob[2*cHW];
        hl4[u] = ob[3*cHW];
        cl4[u] = ob[4*cHW];
        wt4[u] = s_win[cc - winoff];
    }

    // ---- Phase A pass 2: compute (identical math, register inputs) ----
    h2 pl2[2], pr2[2], pt2[2], pb2[2], ov2[2], pa06h[2];
    float conf[4], tcf[4];
    unsigned wbits = 0;
    float bce = 0.0f, sq = 0.0f;
    const h2 z2 = { (_Float16)0.0f, (_Float16)0.0f };
    constexpr float cLN2 = 0.6931471805599453f;

    #pragma unroll
    for (int u = 0; u < 4; ++u) {
        int cell = base + (u << 8);
        bool a_  = cell < cA4;
        int na = na4[u], i = i4[u], j = j4[u];
        float xl = xl4[u], yl = yl4[u], wl = wl4[u], hl = hl4[u], cl = cl4[u];
        // fused sigmoid + softplus: S = 1+e^-l; sigma = rcp(S); bce uses log2(S)
        float Ex = __builtin_amdgcn_exp2f(-1.4426950408889634f * xl);
        float Sx = 1.0f + Ex;
        float x  = frcp(Sx);
        float Lx = __builtin_amdgcn_logf(Sx);
        float Ey = __builtin_amdgcn_exp2f(-1.4426950408889634f * yl);
        float Sy = 1.0f + Ey;
        float y  = frcp(Sy);
        float Ly = __builtin_amdgcn_logf(Sy);
        float cf = frcp(1.0f + fexp(-cl));
        float px = x + (float)i, py = y + (float)j;
        float pw = fexp(wl) * cAW[na], ph = fexp(hl) * cAH[na];
        float l0 = px - 0.5f*pw, r0 = px + 0.5f*pw;
        float t0 = py - 0.5f*ph, b0 = py + 0.5f*ph;
        float pa = pw * ph;
        int p = u >> 1, s = u & 1;
        pl2[p][s] = (_Float16)(cS * l0);  pr2[p][s] = (_Float16)(cS * r0);
        pt2[p][s] = (_Float16)(cS * t0);  pb2[p][s] = (_Float16)(cS * b0);
        pa06h[p][s] = (_Float16)(0.6f * pa);
        ov2[p][s] = (_Float16)0.0f;
        conf[u] = cf;

        float tx = 0.5f, ty = 0.5f, tw = 0.0f, th = 0.0f, tc = 0.0f;
        int wt = wt4[u];
        bool wfl = (wt >= 0) && a_;
        if (wfl) {                         // rare lanes: inline winner values
            wbits |= (1u << u);
            float4 g = s_gt[wt];
            tx = g.x - (float)i;  ty = g.y - (float)j;
            tw = flog(fmaxf(g.z, 1e-12f)) - cLNAW[na];
            th = flog(fmaxf(g.w, 1e-12f)) - cLNAH[na];
            float iw = fminf(r0, g.x + 0.5f*g.z) - fmaxf(l0, g.x - 0.5f*g.z);
            float ih = fminf(b0, g.y + 0.5f*g.w) - fmaxf(t0, g.y - 0.5f*g.w);
            iw = fmaxf(iw, 0.0f); ih = fmaxf(ih, 0.0f);
            float inter = iw * ih;
            float uni   = g.z * g.w + pa - inter;
            tc = inter * frcp(fmaxf(uni, 1e-12f));
        }
        tcf[u] = tc;
        if (a_) {
            bce += (1.0f - tx) * xl + cLN2 * Lx;
            bce += (1.0f - ty) * yl + cLN2 * Ly;
            float dw = wl - tw, dh = hl - th;
            sq += dw*dw + dh*dh;
        }
    }

    // ---- Phase B: any-target IoU > 0.6, packed f16 ----
    // GB: uniform readonly loads -> scalar pipe (zero LDS/VALU cost)
    // iw clamped >=0; ih unclamped (negative contribution can't flip test)
    #pragma unroll 10
    for (int t = 0; t < cT; ++t) {
        unsigned w0, w1, w2, w3, w4;
        if constexpr (GB) {
            uint4 bx = gb4[nbT + t];
            w0 = bx.x; w1 = bx.y; w2 = bx.z; w3 = bx.w;
            w4 = gb1[nbT + t];
        } else {
            uint4 bx = *(const uint4*)&s_box[t][0];
            w0 = bx.x; w1 = bx.y; w2 = bx.z; w3 = bx.w;
            w4 = s_box[t][4];
        }
        HU a, b, c, d, e;
        a.u = w0; b.u = w1; c.u = w2; d.u = w3; e.u = w4;
        #pragma unroll
        for (int p = 0; p < 2; ++p) {
            h2 iw = __builtin_elementwise_min(pr2[p], b.h) - __builtin_elementwise_max(pl2[p], a.h);
            h2 ih = __builtin_elementwise_min(pb2[p], d.h) - __builtin_elementwise_max(pt2[p], c.h);
            iw = __builtin_elementwise_max(iw, z2);
            ov2[p] = __builtin_elementwise_max(ov2[p], iw * ih + e.h);  // v_pk_fma
        }
    }

    // ---- epilogue: conf loss ----
    float sc = 0.0f;
    #pragma unroll
    for (int u = 0; u < 4; ++u) {
        int cell = base + (u << 8);
        if (cell >= cA4) continue;
        int p = u >> 1, s = u & 1;
        bool wfl  = (wbits >> u) & 1;
        bool over = ov2[p][s] > pa06h[p][s];
        float cm  = wfl ? 1.0f : (over ? 0.0f : 1.0f);
        float d   = (conf[u] - tcf[u]) * cm;
        sc += d * d;
    }

    // ---- block reduction -> banked double atomics ----
    double v0 = (double)bce, v1 = (double)sq, v2 = (double)sc;
    for (int off = 32; off > 0; off >>= 1) {
        v0 += __shfl_down(v0, off);
        v1 += __shfl_down(v1, off);
        v2 += __shfl_down(v2, off);
    }
    int lane = tid & 63, wid = tid >> 6;
    if (lane == 0) { s_red[0][wid] = v0; s_red[1][wid] = v1; s_red[2][wid] = v2; }
    __syncthreads();
    if (tid == 0) {
        double a0 = s_red[0][0] + s_red[0][1] + s_red[0][2] + s_red[0][3];
        double a1 = s_red[1][0] + s_red[1][1] + s_red[1][2] + s_red[1][3];
        double a2 = s_red[2][0] + s_red[2][1] + s_red[2][2] + s_red[2][3];
        int bank = blockIdx.x & (ACC_BANKS - 1);
        atomicAdd(&acc[0*ACC_BANKS + bank], a0);
        atomicAdd(&acc[1*ACC_BANKS + bank], a1);
        atomicAdd(&acc[2*ACC_BANKS + bank], a2);
    }
}

// =====================================================================
// K2: class NLL. rowenc read FIRST; 20-plane LSE only in selected
// lanes (~10/361 per block).  (R10 verbatim)
// =====================================================================
__launch_bounds__(384)
__global__ void k_cls(const float* __restrict__ outp, const float* __restrict__ target,
                      const int* __restrict__ rowenc, double* __restrict__ acc,
                      int* __restrict__ cnt, float* __restrict__ out) {
    __shared__ double s_red[2][6];
    __shared__ int s_last;
    const int tid = threadIdx.x;
    const int b   = blockIdx.x / cNA;
    const int na  = blockIdx.x - b * cNA;
    double nll = 0.0, ns = 0.0;
    if (tid < cHW) {
        const int rem = tid;
        int v = rowenc[b * cA4 + na * cHW + rem];
        if ((v >> 10) == 1) {                 // exactly one class set
            const float* ob = outp + ((size_t)(b * cC) * cCH + na * 6 + 5) * cHW + rem;
            float l[cC]; float m = -1e30f;
            #pragma unroll
            for (int c = 0; c < cC; ++c) {
                l[c] = ob[(size_t)c * (cCH * cHW)];
                m = fmaxf(m, l[c]);
            }
            float s = 0.0f;
            #pragma unroll
            for (int c = 0; c < cC; ++c) s += fexp(l[c] - m);
            float lse = m + flog(s);
            int payload = v & 1023;
            int selc = payload / cT;
            int selt = payload - selc * cT;
            int label = (int)target[((size_t)(b * cC + selc) * cT + selt) * 5];
            nll = (double)(lse - l[label]);
            ns  = 1.0;
        }
    }
    for (int off = 32; off > 0; off >>= 1) {
        nll += __shfl_down(nll, off);
        ns  += __shfl_down(ns, off);
    }
    int lane = tid & 63, wid = tid >> 6;
    if (lane == 0) { s_red[0][wid] = nll; s_red[1][wid] = ns; }
    __syncthreads();
    if (tid == 0) {
        double a0 = 0.0, a1 = 0.0;
        #pragma unroll
        for (int w = 0; w < 6; ++w) { a0 += s_red[0][w]; a1 += s_red[1][w]; }
        int bank = blockIdx.x & (ACC_BANKS - 1);
        atomicAdd(&acc[3*ACC_BANKS + bank], a0);
        atomicAdd(&acc[4*ACC_BANKS + bank], a1);
        __threadfence();                                  // release
        s_last = (atomicAdd(cnt, 1) == cCLS_BLOCKS - 1);
    }
    __syncthreads();
    if (s_last && tid < 64) {
        __threadfence();                                  // acquire
        double s[5];
        #pragma unroll
        for (int j = 0; j < 5; ++j) {
            // atomic read-with-add-0: device-coherent across XCD L2s
            double v = atomicAdd(&acc[j * ACC_BANKS + tid], 0.0);
            for (int off = 32; off > 0; off >>= 1) v += __shfl_down(v, off);
            s[j] = v;
        }
        if (tid == 0) {
            double Ninv = 1.0 / (double)cNTOT;
            double loss = s[0] * Ninv            // loss_x + loss_y
                        + 0.5 * s[1] * Ninv      // loss_w + loss_h
                        + 0.5 * s[2] * Ninv      // loss_conf
                        + s[3] / fmax(s[4], 1.0);// loss_cls
            out[0] = (float)loss;
        }
    }
}

extern "C" void kernel_launch(void* const* d_in, const int* in_sizes, int n_in,
                              void* d_out, int out_size, void* d_ws, size_t ws_size,
                              hipStream_t stream) {
    const float* output = (const float*)d_in[0];
    const float* target = (const float*)d_in[1];
    char* ws = (char*)d_ws;
    double*   acc    = (double*)ws;
    int*      cnt    = (int*)(ws + OFF_CNT);
    int*      rowenc = (int*)(ws + OFF_ROW);
    uint4*    gb4    = (uint4*)(ws + OFF_GB4);
    unsigned* gb1    = (unsigned*)(ws + OFF_GB1);

    if (ws_size >= WS_NEEDED) {
        // 3 nodes: k_init (zero + tables), k_main (GB), k_cls
        k_init<<<cCLS_BLOCKS, 256, 0, stream>>>(target, (int4*)ws, gb4, gb1);
        k_main<true><<<cNB * 2, 256, 0, stream>>>(output, target, gb4, gb1, rowenc, acc);
    } else {
        // fallback: memset + LDS-box k_main (no global tables touched)
        hipMemsetAsync(ws, 0, ZERO_BYTES, stream);
        k_main<false><<<cNB * 2, 256, 0, stream>>>(output, target, gb4, gb1, rowenc, acc);
    }
    k_cls<<<cCLS_BLOCKS, 384, 0, stream>>>(output, target, rowenc, acc, cnt, (float*)d_out);
}

// Round 12
// 126.504 us; speedup vs baseline: 1.0102x; 1.0102x over previous
//
#include <hip/hip_runtime.h>
#include <math.h>

// ---- problem constants ----
constexpr int cB   = 64;
constexpr int cC   = 20;
constexpr int cNA  = 5;
constexpr int cH   = 19;
constexpr int cW   = 19;
constexpr int cT   = 50;
constexpr int cNB  = cB * cC;          // 1280
constexpr int cHW  = cH * cW;          // 361
constexpr int cA4  = cNA * cHW;        // 1805
constexpr int cCH  = cNA * 6;          // 30 channels
constexpr long cNTOT = (long)cNB * cA4; // 2,310,400
constexpr int cCLS_BLOCKS = cB * cNA;  // 320

// ---- anchors: compile-time (match setup_inputs exactly) ----
__device__ __constant__ float cAW[cNA]   = {1.3221f, 3.19275f, 5.05587f, 9.47112f, 11.2364f};
__device__ __constant__ float cAH[cNA]   = {1.73145f, 4.00944f, 8.09892f, 4.84053f, 10.0071f};
__device__ __constant__ float cAREA[cNA] = {2.28930345f, 12.80114796f, 40.94706183f, 45.84455262f, 112.44377644f};
__device__ __constant__ float cLNAW[cNA] = {0.27920469f, 1.16088088f, 1.62060702f, 2.24822684f, 2.41915174f};
__device__ __constant__ float cLNAH[cNA] = {0.54896100f, 1.38865236f, 2.09173157f, 1.57701337f, 2.30329495f};

// ---- workspace layout (bytes) ----
constexpr int ACC_BANKS = 64;
constexpr size_t OFF_CNT = 2560;                // after 5*64 doubles
constexpr size_t OFF_ROW = 4096;                // rowenc: cB*cA4 ints = 462080 B
constexpr size_t ZERO_BYTES = OFF_ROW + (size_t)cB * cA4 * 4;   // 466176 (16-divisible)
constexpr int    ZERO_INT4  = (int)(ZERO_BYTES / 16);           // 29136
// box tables (fully overwritten by k_init; NOT zeroed)
constexpr size_t OFF_GB4 = 466432;                               // uint4 [cNB*cT] splat2 l,r,t,b
constexpr size_t OFF_GB1 = OFF_GB4 + (size_t)cNB * cT * 16;      // u32   [cNB*cT] splat2 -0.6*ga
constexpr size_t WS_NEEDED = OFF_GB1 + (size_t)cNB * cT * 4;     // 1,746,432

// ---- fast transcendentals (raw HW ops) ----
__device__ __forceinline__ float fexp(float x) {
    return __builtin_amdgcn_exp2f(x * 1.4426950408889634f);
}
__device__ __forceinline__ float flog(float x) {
    return __builtin_amdgcn_logf(x) * 0.6931471805599453f;
}
__device__ __forceinline__ float frcp(float x) { return __builtin_amdgcn_rcpf(x); }

// ---- packed f16 helpers ----
typedef _Float16 h2 __attribute__((ext_vector_type(2)));
union HU { unsigned u; h2 h; };
__device__ __forceinline__ unsigned splat2(float v) {
    HU x; _Float16 f = (_Float16)v; x.h[0] = f; x.h[1] = f; return x.u;
}
// boxes pre-scaled by sqrt(1.6): inner test is pk_fma(iw,ih,-0.6ga) > 0.6pa
constexpr float cS = 1.2649110640673518f;   // sqrt(1.6)

// =====================================================================
// K0 (init): replaces BOTH the memset node and k_prep.
// =====================================================================
__launch_bounds__(256)
__global__ void k_init(const float* __restrict__ target, int4* __restrict__ wsz,
                       uint4* __restrict__ gb4, unsigned* __restrict__ gb1) {
    const int gtid = blockIdx.x * 256 + threadIdx.x;
    int4 z4; z4.x = z4.y = z4.z = z4.w = 0;
    for (int k = gtid; k < ZERO_INT4; k += cCLS_BLOCKS * 256) wsz[k] = z4;

    const int nb = blockIdx.x * 4 + (threadIdx.x >> 6);
    const int t  = threadIdx.x & 63;
    float xr = 1.f, yr = 0.f, wr = 0.f, hr = 0.f;
    const bool isT = (t < cT);
    if (isT) {
        const float* tg = target + (size_t)nb * (cT * 5) + t * 5;
        xr = tg[1]; yr = tg[2]; wr = tg[3]; hr = tg[4];
    }
    unsigned long long nz = __ballot(xr != 0.0f);
    if (isT) {
        unsigned long long below = (2ull << t) - 1ull;
        bool valid = ((~nz) & below) == 0ull;
        const int idx = nb * cT + t;
        float gx = xr * (float)cW, gy = yr * (float)cH;
        float gw = wr * (float)cW, gh = hr * (float)cH;
        uint4 bx;
        if (valid) {
            bx.x = splat2(cS * (gx - 0.5f * gw));
            bx.y = splat2(cS * (gx + 0.5f * gw));
            bx.z = splat2(cS * (gy - 0.5f * gh));
            bx.w = splat2(cS * (gy + 0.5f * gh));
            gb1[idx] = splat2(-0.6f * (gw * gh));
        } else {                              // degenerate: inter == 0
            bx.x = splat2(1e4f);  bx.y = splat2(-1e4f);
            bx.z = splat2(1e4f);  bx.w = splat2(-1e4f);
            gb1[idx] = splat2(0.0f);
        }
        gb4[idx] = bx;
    }
}

// =====================================================================
// K1: per-cell losses. 2 blocks per nb, 4 cells/thread (proven shape),
// XCD-chunked swizzle; Phase B boxes via uniform readonly scalar loads.
// =====================================================================
template<bool GB>
__launch_bounds__(256, 4)
__global__ void k_main(const float* __restrict__ outp, const float* __restrict__ target,
                       const uint4* __restrict__ gb4, const unsigned* __restrict__ gb1,
                       int* __restrict__ rowenc, double* __restrict__ acc) {
    __shared__ int s_win[1024];                      // windowed winner table
    __shared__ float4 s_gt[cT];                      // gx,gy,gw,gh
    __shared__ __align__(16) unsigned s_box[GB ? 1 : cT][8];  // fallback only
    __shared__ double s_red[3][4];
    const int tid  = threadIdx.x;
    // 2560 = 8 XCD-chunks of 320; halves of an nb stay on one XCD
    const int swz  = ((int)(blockIdx.x & 7)) * 320 + ((int)blockIdx.x >> 3);
    const int nb   = swz >> 1;
    const int half = swz & 1;
    const int winoff = half << 10;
    const int base = winoff + tid;                   // 0..1023 / 1024..2047
    const int b_   = nb / cC;
    const int c_   = nb - b_ * cC;
    const float* obase = outp + (size_t)nb * (cCH * cHW);
    const int nbT = nb * cT;

    s_win[tid] = -1; s_win[tid + 256] = -1;
    s_win[tid + 512] = -1; s_win[tid + 768] = -1;
    __syncthreads();

    // ---- light prep (wave 0; both halves duplicate) ----
    int myCell = -1;                                 // register-carried winner cell
    if (tid < 64) {
        const int t = tid;
        float xr = 1.f, yr = 0.f, wr = 0.f, hr = 0.f;
        if (t < cT) {
            const float* tg = target + (size_t)nb * (cT * 5) + t * 5;
            xr = tg[1]; yr = tg[2]; wr = tg[3]; hr = tg[4];
        }
        unsigned long long nz = __ballot(xr != 0.0f);
        if (t < cT) {
            unsigned long long below = (2ull << t) - 1ull;
            bool valid = ((~nz) & below) == 0ull;
            float gx = xr * (float)cW, gy = yr * (float)cH;
            float gw = wr * (float)cW, gh = hr * (float)cH;
            s_gt[t] = make_float4(gx, gy, gw, gh);
            if (valid) {
                float garea = gw * gh;
                float best = -1.0f; int bn = 0;
                for (int n = 0; n < cNA; ++n) {
                    float inter = fminf(gw, cAW[n]) * fminf(gh, cAH[n]);
                    float uni   = garea + cAREA[n] - inter;
                    float r = inter / fmaxf(uni, 1e-12f);
                    if (r > best) { best = r; bn = n; }
                }
                int cell = bn * cHW + (int)gy * cW + (int)gx;
                myCell = cell;
                if constexpr (!GB) {
                    s_box[t][0] = splat2(cS * (gx - 0.5f * gw));
                    s_box[t][1] = splat2(cS * (gx + 0.5f * gw));
                    s_box[t][2] = splat2(cS * (gy - 0.5f * gh));
                    s_box[t][3] = splat2(cS * (gy + 0.5f * gh));
                    s_box[t][4] = splat2(-0.6f * garea);
                }
                if (cell >= winoff && cell < winoff + 1024)
                    atomicMax(&s_win[cell - winoff], t);
            } else if constexpr (!GB) {
                s_box[t][0] = splat2(1e4f);  s_box[t][1] = splat2(-1e4f);
                s_box[t][2] = splat2(1e4f);  s_box[t][3] = splat2(-1e4f);
                s_box[t][4] = splat2(0.0f);
            }
        }
    }
    __syncthreads();
    // rowenc emission: winner of each in-window cell emits (exactly-once)
    if (tid < cT && myCell >= winoff && myCell < winoff + 1024 &&
        s_win[myCell - winoff] == tid)
        atomicAdd(&rowenc[b_ * cA4 + myCell], (1 << 10) | (c_ * cT + tid));

    // ---- Phase A: boxes + bce/sq; winner values inline from s_gt ----
    h2 pl2[2], pr2[2], pt2[2], pb2[2], ov2[2], pa06h[2];
    float conf[4], tcf[4];
    unsigned wbits = 0;
    float bce = 0.0f, sq = 0.0f;
    const h2 z2 = { (_Float16)0.0f, (_Float16)0.0f };
    constexpr float cLN2 = 0.6931471805599453f;

    #pragma unroll
    for (int u = 0; u < 4; ++u) {
        int cell = base + (u << 8);
        bool a_  = cell < cA4;
        int cc   = a_ ? cell : (cA4 - 1);
        int na   = cc / cHW;
        int rem  = cc - na * cHW;
        int j    = rem / cW;
        int i    = rem - j * cW;
        const float* ob = obase + (size_t)(na * 6) * cHW + rem;
        float xl = ob[0], yl = ob[cHW], wl = ob[2*cHW], hl = ob[3*cHW], cl = ob[4*cHW];
        // fused sigmoid + softplus: S = 1+e^-l; sigma = rcp(S); bce uses log2(S)
        float Ex = __builtin_amdgcn_exp2f(-1.4426950408889634f * xl);
        float Sx = 1.0f + Ex;
        float x  = frcp(Sx);
        float Lx = __builtin_amdgcn_logf(Sx);
        float Ey = __builtin_amdgcn_exp2f(-1.4426950408889634f * yl);
        float Sy = 1.0f + Ey;
        float y  = frcp(Sy);
        float Ly = __builtin_amdgcn_logf(Sy);
        float cf = frcp(1.0f + fexp(-cl));
        float px = x + (float)i, py = y + (float)j;
        float pw = fexp(wl) * cAW[na], ph = fexp(hl) * cAH[na];
        float l0 = px - 0.5f*pw, r0 = px + 0.5f*pw;
        float t0 = py - 0.5f*ph, b0 = py + 0.5f*ph;
        float pa = pw * ph;
        int p = u >> 1, s = u & 1;
        pl2[p][s] = (_Float16)(cS * l0);  pr2[p][s] = (_Float16)(cS * r0);
        pt2[p][s] = (_Float16)(cS * t0);  pb2[p][s] = (_Float16)(cS * b0);
        pa06h[p][s] = (_Float16)(0.6f * pa);
        ov2[p][s] = (_Float16)0.0f;
        conf[u] = cf;

        float tx = 0.5f, ty = 0.5f, tw = 0.0f, th = 0.0f, tc = 0.0f;
        int wt = s_win[cc - winoff];
        bool wfl = (wt >= 0) && a_;
        if (wfl) {                         // rare lanes: inline winner values
            wbits |= (1u << u);
            float4 g = s_gt[wt];
            tx = g.x - (float)i;  ty = g.y - (float)j;
            tw = flog(fmaxf(g.z, 1e-12f)) - cLNAW[na];
            th = flog(fmaxf(g.w, 1e-12f)) - cLNAH[na];
            float iw = fminf(r0, g.x + 0.5f*g.z) - fmaxf(l0, g.x - 0.5f*g.z);
            float ih = fminf(b0, g.y + 0.5f*g.w) - fmaxf(t0, g.y - 0.5f*g.w);
            iw = fmaxf(iw, 0.0f); ih = fmaxf(ih, 0.0f);
            float inter = iw * ih;
            float uni   = g.z * g.w + pa - inter;
            tc = inter * frcp(fmaxf(uni, 1e-12f));
        }
        tcf[u] = tc;
        if (a_) {
            bce += (1.0f - tx) * xl + cLN2 * Lx;
            bce += (1.0f - ty) * yl + cLN2 * Ly;
            float dw = wl - tw, dh = hl - th;
            sq += dw*dw + dh*dh;
        }
    }

    // ---- Phase B: any-target IoU > 0.6, packed f16 ----
    // GB: uniform readonly loads -> scalar pipe (zero LDS/VALU cost)
    // iw clamped >=0; ih unclamped (negative contribution can't flip test)
    #pragma unroll 10
    for (int t = 0; t < cT; ++t) {
        unsigned w0, w1, w2, w3, w4;
        if constexpr (GB) {
            uint4 bx = gb4[nbT + t];
            w0 = bx.x; w1 = bx.y; w2 = bx.z; w3 = bx.w;
            w4 = gb1[nbT + t];
        } else {
            uint4 bx = *(const uint4*)&s_box[t][0];
            w0 = bx.x; w1 = bx.y; w2 = bx.z; w3 = bx.w;
            w4 = s_box[t][4];
        }
        HU a, b, c, d, e;
        a.u = w0; b.u = w1; c.u = w2; d.u = w3; e.u = w4;
        #pragma unroll
        for (int p = 0; p < 2; ++p) {
            h2 iw = __builtin_elementwise_min(pr2[p], b.h) - __builtin_elementwise_max(pl2[p], a.h);
            h2 ih = __builtin_elementwise_min(pb2[p], d.h) - __builtin_elementwise_max(pt2[p], c.h);
            iw = __builtin_elementwise_max(iw, z2);
            ov2[p] = __builtin_elementwise_max(ov2[p], iw * ih + e.h);  // v_pk_fma
        }
    }

    // ---- epilogue: conf loss ----
    float sc = 0.0f;
    #pragma unroll
    for (int u = 0; u < 4; ++u) {
        int cell = base + (u << 8);
        if (cell >= cA4) continue;
        int p = u >> 1, s = u & 1;
        bool wfl  = (wbits >> u) & 1;
        bool over = ov2[p][s] > pa06h[p][s];
        float cm  = wfl ? 1.0f : (over ? 0.0f : 1.0f);
        float d   = (conf[u] - tcf[u]) * cm;
        sc += d * d;
    }

    // ---- block reduction -> banked double atomics ----
    double v0 = (double)bce, v1 = (double)sq, v2 = (double)sc;
    for (int off = 32; off > 0; off >>= 1) {
        v0 += __shfl_down(v0, off);
        v1 += __shfl_down(v1, off);
        v2 += __shfl_down(v2, off);
    }
    int lane = tid & 63, wid = tid >> 6;
    if (lane == 0) { s_red[0][wid] = v0; s_red[1][wid] = v1; s_red[2][wid] = v2; }
    __syncthreads();
    if (tid == 0) {
        double a0 = s_red[0][0] + s_red[0][1] + s_red[0][2] + s_red[0][3];
        double a1 = s_red[1][0] + s_red[1][1] + s_red[1][2] + s_red[1][3];
        double a2 = s_red[2][0] + s_red[2][1] + s_red[2][2] + s_red[2][3];
        int bank = blockIdx.x & (ACC_BANKS - 1);
        atomicAdd(&acc[0*ACC_BANKS + bank], a0);
        atomicAdd(&acc[1*ACC_BANKS + bank], a1);
        atomicAdd(&acc[2*ACC_BANKS + bank], a2);
    }
}

// =====================================================================
// K2: class NLL. rowenc read FIRST; 20-plane LSE only in selected
// lanes (~10/361 per block).
// =====================================================================
__launch_bounds__(384)
__global__ void k_cls(const float* __restrict__ outp, const float* __restrict__ target,
                      const int* __restrict__ rowenc, double* __restrict__ acc,
                      int* __restrict__ cnt, float* __restrict__ out) {
    __shared__ double s_red[2][6];
    __shared__ int s_last;
    const int tid = threadIdx.x;
    const int b   = blockIdx.x / cNA;
    const int na  = blockIdx.x - b * cNA;
    double nll = 0.0, ns = 0.0;
    if (tid < cHW) {
        const int rem = tid;
        int v = rowenc[b * cA4 + na * cHW + rem];
        if ((v >> 10) == 1) {                 // exactly one class set
            const float* ob = outp + ((size_t)(b * cC) * cCH + na * 6 + 5) * cHW + rem;
            float l[cC]; float m = -1e30f;
            #pragma unroll
            for (int c = 0; c < cC; ++c) {
                l[c] = ob[(size_t)c * (cCH * cHW)];
                m = fmaxf(m, l[c]);
            }
            float s = 0.0f;
            #pragma unroll
            for (int c = 0; c < cC; ++c) s += fexp(l[c] - m);
            float lse = m + flog(s);
            int payload = v & 1023;
            int selc = payload / cT;
            int selt = payload - selc * cT;
            int label = (int)target[((size_t)(b * cC + selc) * cT + selt) * 5];
            nll = (double)(lse - l[label]);
            ns  = 1.0;
        }
    }
    for (int off = 32; off > 0; off >>= 1) {
        nll += __shfl_down(nll, off);
        ns  += __shfl_down(ns, off);
    }
    int lane = tid & 63, wid = tid >> 6;
    if (lane == 0) { s_red[0][wid] = nll; s_red[1][wid] = ns; }
    __syncthreads();
    if (tid == 0) {
        double a0 = 0.0, a1 = 0.0;
        #pragma unroll
        for (int w = 0; w < 6; ++w) { a0 += s_red[0][w]; a1 += s_red[1][w]; }
        int bank = blockIdx.x & (ACC_BANKS - 1);
        atomicAdd(&acc[3*ACC_BANKS + bank], a0);
        atomicAdd(&acc[4*ACC_BANKS + bank], a1);
        __threadfence();                                  // release
        s_last = (atomicAdd(cnt, 1) == cCLS_BLOCKS - 1);
    }
    __syncthreads();
    if (s_last && tid < 64) {
        __threadfence();                                  // acquire
        double s[5];
        #pragma unroll
        for (int j = 0; j < 5; ++j) {
            // atomic read-with-add-0: device-coherent across XCD L2s
            double v = atomicAdd(&acc[j * ACC_BANKS + tid], 0.0);
            for (int off = 32; off > 0; off >>= 1) v += __shfl_down(v, off);
            s[j] = v;
        }
        if (tid == 0) {
            double Ninv = 1.0 / (double)cNTOT;
            double loss = s[0] * Ninv            // loss_x + loss_y
                        + 0.5 * s[1] * Ninv      // loss_w + loss_h
                        + 0.5 * s[2] * Ninv      // loss_conf
                        + s[3] / fmax(s[4], 1.0);// loss_cls
            out[0] = (float)loss;
        }
    }
}

extern "C" void kernel_launch(void* const* d_in, const int* in_sizes, int n_in,
                              void* d_out, int out_size, void* d_ws, size_t ws_size,
                              hipStream_t stream) {
    const float* output = (const float*)d_in[0];
    const float* target = (const float*)d_in[1];
    char* ws = (char*)d_ws;
    double*   acc    = (double*)ws;
    int*      cnt    = (int*)(ws + OFF_CNT);
    int*      rowenc = (int*)(ws + OFF_ROW);
    uint4*    gb4    = (uint4*)(ws + OFF_GB4);
    unsigned* gb1    = (unsigned*)(ws + OFF_GB1);

    if (ws_size >= WS_NEEDED) {
        // 3 nodes: k_init (zero + tables), k_main (GB), k_cls
        k_init<<<cCLS_BLOCKS, 256, 0, stream>>>(target, (int4*)ws, gb4, gb1);
        k_main<true><<<cNB * 2, 256, 0, stream>>>(output, target, gb4, gb1, rowenc, acc);
    } else {
        // fallback: memset + LDS-box k_main (no global tables touched)
        hipMemsetAsync(ws, 0, ZERO_BYTES, stream);
        k_main<false><<<cNB * 2, 256, 0, stream>>>(output, target, gb4, gb1, rowenc, acc);
    }
    k_cls<<<cCLS_BLOCKS, 384, 0, stream>>>(output, target, rowenc, acc, cnt, (float*)d_out);
}